// Round 2
// baseline (245.271 us; speedup 1.0000x reference)
//
#include <hip/hip_runtime.h>

#define NB 64
#define NN 100
#define DL 32
#define BN (NB * NN)  // 6400

typedef short short8 __attribute__((ext_vector_type(8)));
typedef float f32x4 __attribute__((ext_vector_type(4)));

static __device__ __forceinline__ unsigned short f2bf(float f) {
    unsigned int u = __float_as_uint(f);
    unsigned int r = (u + 0x7fffu + ((u >> 16) & 1u)) >> 16;
    return (unsigned short)r;
}
static __device__ __forceinline__ float bf2f(unsigned short s) {
    return __uint_as_float(((unsigned int)s) << 16);
}
static __device__ __forceinline__ float lrelu(float x) { return fmaxf(x, 0.1f * x); }

// Pre-split W1 (both steps) into bf16 hi/lo, stored in MFMA-B-fragment order:
// PW[step][term][kt][half][lane][jj] ushort; B elem = W1[c=half*32+q*8+jj][k=kt*16+kk]
__global__ void k_prepw(const float* __restrict__ w1a, const float* __restrict__ w1b,
                        unsigned short* __restrict__ PW) {
    int o = blockIdx.x * 256 + threadIdx.x;  // 0..16383
    int step = o >> 13, r = o & 8191;
    int jj = r & 7, ln = (r >> 3) & 63, hf = (r >> 9) & 1, kt = (r >> 10) & 3, term = r >> 12;
    int kk = ln & 15, q = ln >> 4;
    int c = hf * 32 + q * 8 + jj, k = kt * 16 + kk;
    const float* w1 = step ? w1b : w1a;
    float wv = w1[c * 64 + k];
    unsigned short hi = f2bf(wv);
    PW[o] = term ? f2bf(wv - bf2f(hi)) : hi;
}

// Fused h = x@lin_w+lin_b (per (b,n) row) and U/V precompute for step 0.
__global__ void k_lin_uv(const float* __restrict__ x, const float* __restrict__ lw,
                         const float* __restrict__ lb, const float* __restrict__ ew0,
                         const float* __restrict__ eb0, float* __restrict__ h,
                         float* __restrict__ U, float* __restrict__ V) {
    __shared__ float hs[DL];
    int bn = blockIdx.x;
    int b = bn / NN, n = bn % NN;
    int t = threadIdx.x;
    if (t < DL) {
        const float* xr = x + b * DL;
        float s = lb[n * DL + t];
#pragma unroll
        for (int c = 0; c < DL; ++c) s += xr[c] * lw[c * 3200 + n * DL + t];
        hs[t] = s;
        h[bn * DL + t] = s;
    }
    __syncthreads();
    int k = t & 63, which = t >> 6;
    const float* wp = ew0 + (which ? DL * 64 : 0) + k;
    float s = which ? 0.f : eb0[k];
#pragma unroll
    for (int c = 0; c < DL; ++c) s += hs[c] * wp[c * 64];
    (which ? V : U)[bn * 64 + k] = s;
}

// Fused edge MLP + j-aggregation. Block = (b,i); wave w owns j-tiles {w, w+4}.
// A-fragments built directly in registers (no P LDS, no in-loop barriers).
// Precision: A_hi * (B_hi + B_lo) split-bf16 (2 terms).
__global__ __launch_bounds__(256, 2) void k_edge(
    const float* __restrict__ h, const float* __restrict__ U, const float* __restrict__ V,
    const float* __restrict__ w0, const unsigned short* __restrict__ PW,
    const float* __restrict__ b1, float* __restrict__ agg) {
    __shared__ float dist[112];
    __shared__ float red[4][64];

    int bi = blockIdx.x;
    int b = bi / NN;
    int t = threadIdx.x;
    int w = t >> 6, lane = t & 63, q = lane >> 4, kk = lane & 15;

    // distances dist[i, j] for all j (clamped beyond 99; masked in epilogue)
    if (t < 112) {
        int j = t < NN ? t : NN - 1;
        const float4* hi4 = (const float4*)(h + bi * DL);
        const float4* hj4 = (const float4*)(h + (b * NN + j) * DL);
        float s = 0.f;
#pragma unroll
        for (int r = 0; r < 8; ++r) {
            float4 a = hi4[r], c = hj4[r];
            float d0 = a.x - c.x, d1 = a.y - c.y, d2 = a.z - c.z, d3 = a.w - c.w;
            s += d0 * d0 + d1 * d1 + d2 * d2 + d3 * d3;
        }
        dist[t] = sqrtf(s + 1e-12f);
    }

    // Per-lane invariant channels: c in [q*8, q*8+8) and [32+q*8, 32+q*8+8)
    int cb = q * 8;
    float ui[16], wdv[16];
    {
        const float* Up = U + bi * 64;
        const float* Wd = w0 + 64 * 64;  // dist row of W0
#pragma unroll
        for (int e = 0; e < 8; ++e) {
            ui[e] = Up[cb + e];
            ui[8 + e] = Up[32 + cb + e];
            wdv[e] = Wd[cb + e];
            wdv[8 + e] = Wd[32 + cb + e];
        }
    }

    // B fragments: all 4 k-tiles, both K-halves, hi+lo terms (pre-swizzled)
    short8 Bh[4][2], Bl[4][2];
    {
        const short8* pw = (const short8*)PW;
#pragma unroll
        for (int kt = 0; kt < 4; ++kt)
#pragma unroll
            for (int hf = 0; hf < 2; ++hf) {
                Bh[kt][hf] = pw[(kt * 2 + hf) * 64 + lane];
                Bl[kt][hf] = pw[512 + (kt * 2 + hf) * 64 + lane];
            }
    }
    float b1v[4];
#pragma unroll
    for (int kt = 0; kt < 4; ++kt) b1v[kt] = b1[kt * 16 + kk];

    f32x4 sacc = {0.f, 0.f, 0.f, 0.f};
    __syncthreads();

    for (int jt = w; jt < 7; jt += 4) {
        int j = jt * 16 + kk;  // A row m = lane&15
        int jc = j < NN ? j : NN - 1;
        float dj = dist[j];
        const float* vr = V + (size_t)(b * NN + jc) * 64;

        short8 A0, A1;
#pragma unroll
        for (int e = 0; e < 8; ++e) {
            float p = lrelu(ui[e] + vr[cb + e] + dj * wdv[e]);
            A0[e] = (short)f2bf(p);
        }
#pragma unroll
        for (int e = 0; e < 8; ++e) {
            float p = lrelu(ui[8 + e] + vr[32 + cb + e] + dj * wdv[8 + e]);
            A1[e] = (short)f2bf(p);
        }

#pragma unroll
        for (int kt = 0; kt < 4; ++kt) {
            f32x4 a = {0.f, 0.f, 0.f, 0.f};
            a = __builtin_amdgcn_mfma_f32_16x16x32_bf16(A0, Bh[kt][0], a, 0, 0, 0);
            a = __builtin_amdgcn_mfma_f32_16x16x32_bf16(A1, Bh[kt][1], a, 0, 0, 0);
            a = __builtin_amdgcn_mfma_f32_16x16x32_bf16(A0, Bl[kt][0], a, 0, 0, 0);
            a = __builtin_amdgcn_mfma_f32_16x16x32_bf16(A1, Bl[kt][1], a, 0, 0, 0);
#pragma unroll
            for (int r = 0; r < 4; ++r) {
                int jr = jt * 16 + q * 4 + r;  // C/D row
                float y = a[r] + b1v[kt];
                sacc[kt] += (jr < NN) ? lrelu(y) : 0.f;
            }
        }
    }

    // reduce over q within wave, then across waves via LDS
#pragma unroll
    for (int kt = 0; kt < 4; ++kt) {
        float s = sacc[kt];
        s += __shfl_xor(s, 16);
        s += __shfl_xor(s, 32);
        if (q == 0) red[w][kt * 16 + kk] = s;
    }
    __syncthreads();
    if (t < 64) agg[bi * 64 + t] = red[0][t] + red[1][t] + red[2][t] + red[3][t];
}

// Fused node MLP (two layers) + U/V precompute for the next step. 4 n per block.
__global__ void k_node_uv(const float* __restrict__ h, const float* __restrict__ agg,
                          const float* __restrict__ w0n, const float* __restrict__ b0n,
                          const float* __restrict__ w1n, const float* __restrict__ b1n,
                          const float* __restrict__ ew0, const float* __restrict__ eb0,
                          float* __restrict__ hout, float* __restrict__ U,
                          float* __restrict__ V) {
    __shared__ float t0s[4][64];
    __shared__ float hs[4][DL];
    int t = threadIdx.x;
    int n0 = blockIdx.x * 4;
    {
        int k = t & 63, ni = t >> 6;
        const float* hr = h + (n0 + ni) * DL;
        const float* ar = agg + (n0 + ni) * 64;
        float s = b0n[k];
#pragma unroll
        for (int c = 0; c < DL; ++c) s += hr[c] * w0n[c * 64 + k];
#pragma unroll
        for (int c = 0; c < 64; ++c) s += ar[c] * w0n[(DL + c) * 64 + k];
        t0s[ni][k] = lrelu(s);
    }
    __syncthreads();
    if (t < 128) {
        int k = t & 31, ni = t >> 5;
        const float* tr = t0s[ni];
        float s = b1n[k];
#pragma unroll
        for (int c = 0; c < 64; ++c) s += tr[c] * w1n[c * DL + k];
        s = lrelu(s);
        hs[ni][k] = s;
        hout[(n0 + ni) * DL + k] = s;
    }
    __syncthreads();
#pragma unroll
    for (int rpt = 0; rpt < 2; ++rpt) {
        int o = rpt * 256 + t;
        int k = o & 63, which = (o >> 6) & 1, ni = o >> 7;
        const float* hr = hs[ni];
        const float* wp = ew0 + (which ? DL * 64 : 0) + k;
        float s = which ? 0.f : eb0[k];
#pragma unroll
        for (int c = 0; c < DL; ++c) s += hr[c] * wp[c * 64];
        (which ? V : U)[(n0 + ni) * 64 + k] = s;
    }
}

// Fused node MLP (two layers) + final projection + tanh. 4 n per block.
__global__ void k_node_out(const float* __restrict__ h, const float* __restrict__ agg,
                           const float* __restrict__ w0n, const float* __restrict__ b0n,
                           const float* __restrict__ w1n, const float* __restrict__ b1n,
                           const float* __restrict__ ow, const float* __restrict__ ob,
                           float* __restrict__ out) {
    __shared__ float t0s[4][64];
    __shared__ float hs[4][DL];
    int t = threadIdx.x;
    int n0 = blockIdx.x * 4;
    {
        int k = t & 63, ni = t >> 6;
        const float* hr = h + (n0 + ni) * DL;
        const float* ar = agg + (n0 + ni) * 64;
        float s = b0n[k];
#pragma unroll
        for (int c = 0; c < DL; ++c) s += hr[c] * w0n[c * 64 + k];
#pragma unroll
        for (int c = 0; c < 64; ++c) s += ar[c] * w0n[(DL + c) * 64 + k];
        t0s[ni][k] = lrelu(s);
    }
    __syncthreads();
    if (t < 128) {
        int k = t & 31, ni = t >> 5;
        const float* tr = t0s[ni];
        float s = b1n[k];
#pragma unroll
        for (int c = 0; c < 64; ++c) s += tr[c] * w1n[c * DL + k];
        hs[ni][k] = lrelu(s);
    }
    __syncthreads();
    if (t < 12) {
        int o = t % 3, ni = t / 3;
        const float* hr = hs[ni];
        float s = ob[o];
#pragma unroll
        for (int c = 0; c < DL; ++c) s += hr[c] * ow[c * 3 + o];
        out[(n0 + ni) * 3 + o] = tanhf(s);
    }
}

extern "C" void kernel_launch(void* const* d_in, const int* in_sizes, int n_in,
                              void* d_out, int out_size, void* d_ws, size_t ws_size,
                              hipStream_t stream) {
    const float* x     = (const float*)d_in[0];
    const float* lin_w = (const float*)d_in[1];
    const float* lin_b = (const float*)d_in[2];
    const float* ew0[2] = {(const float*)d_in[3],  (const float*)d_in[11]};
    const float* eb0[2] = {(const float*)d_in[4],  (const float*)d_in[12]};
    const float* ew1[2] = {(const float*)d_in[5],  (const float*)d_in[13]};
    const float* eb1[2] = {(const float*)d_in[6],  (const float*)d_in[14]};
    const float* nw0[2] = {(const float*)d_in[7],  (const float*)d_in[15]};
    const float* nb0[2] = {(const float*)d_in[8],  (const float*)d_in[16]};
    const float* nw1[2] = {(const float*)d_in[9],  (const float*)d_in[17]};
    const float* nb1[2] = {(const float*)d_in[10], (const float*)d_in[18]};
    const float* ow = (const float*)d_in[19];
    const float* ob = (const float*)d_in[20];
    float* out = (float*)d_out;

    float* h   = (float*)d_ws;            // 6400 x 32
    float* U   = h + 204800;              // 6400 x 64
    float* V   = U + 409600;              // 6400 x 64
    float* agg = V + 409600;              // 6400 x 64
    unsigned short* PW = (unsigned short*)(agg + 409600);  // 2 x 8192 ushort

    k_prepw<<<64, 256, 0, stream>>>(ew1[0], ew1[1], PW);
    k_lin_uv<<<BN, 128, 0, stream>>>(x, lin_w, lin_b, ew0[0], eb0[0], h, U, V);
    k_edge<<<BN, 256, 0, stream>>>(h, U, V, ew0[0], PW, eb1[0], agg);
    k_node_uv<<<BN / 4, 256, 0, stream>>>(h, agg, nw0[0], nb0[0], nw1[0], nb1[0],
                                          ew0[1], eb0[1], h, U, V);
    k_edge<<<BN, 256, 0, stream>>>(h, U, V, ew0[1], PW + 8192, eb1[1], agg);
    k_node_out<<<BN / 4, 256, 0, stream>>>(h, agg, nw0[1], nb0[1], nw1[1], nb1[1],
                                           ow, ob, out);
}

// Round 3
// 230.380 us; speedup vs baseline: 1.0646x; 1.0646x over previous
//
#include <hip/hip_runtime.h>

#define NB 64
#define NN 100
#define DL 32
#define BN (NB * NN)  // 6400

typedef _Float16 f16x8 __attribute__((ext_vector_type(8)));
typedef float f32x4 __attribute__((ext_vector_type(4)));

static __device__ __forceinline__ float lrelu(float x) { return fmaxf(x, 0.1f * x); }

// Fused: h = x@lin_w+lin_b, U/V for step 0, and W1 f16 B-fragment prep (both steps).
// Blocks 0..1599: 4 (b,n) rows each. Blocks 1600..1601: PW for step 0/1.
__global__ __launch_bounds__(256) void k_pre(
    const float* __restrict__ x, const float* __restrict__ lw, const float* __restrict__ lb,
    const float* __restrict__ ew0, const float* __restrict__ eb0,
    const float* __restrict__ w1a, const float* __restrict__ w1b,
    float* __restrict__ h, float* __restrict__ U, float* __restrict__ V,
    _Float16* __restrict__ PW) {
    int blk = blockIdx.x;
    int t = threadIdx.x;
    if (blk >= 1600) {  // B-fragment swizzle: PW[step][kt][hf][lane][jj]
        int step = blk - 1600;
        const float* w1 = step ? w1b : w1a;
        _Float16* dst = PW + step * 4096;
#pragma unroll
        for (int u = 0; u < 16; ++u) {
            int idx = t * 16 + u;
            int jj = idx & 7, lane = (idx >> 3) & 63, hf = (idx >> 9) & 1, kt = idx >> 10;
            int c = hf * 32 + (lane >> 4) * 8 + jj;
            int k = kt * 16 + (lane & 15);
            dst[idx] = (_Float16)w1[c * 64 + k];
        }
        return;
    }
    __shared__ float xs[DL];
    __shared__ float hs[4][DL];
    int row0 = blk * 4;
    int b = row0 / NN;  // 4-row group never crosses a batch boundary (100 % 4 == 0)
    if (t < DL) xs[t] = x[b * DL + t];
    __syncthreads();
    if (t < 128) {
        int ni = t >> 5, c = t & 31;
        int n = (row0 + ni) % NN;
        float s = lb[n * DL + c];
#pragma unroll
        for (int cc = 0; cc < DL; ++cc) s += xs[cc] * lw[cc * 3200 + n * DL + c];
        hs[ni][c] = s;
        h[(row0 + ni) * DL + c] = s;
    }
    __syncthreads();
#pragma unroll
    for (int r = 0; r < 2; ++r) {
        int o = r * 256 + t;  // 0..511 : 4 rows x (64 U + 64 V)
        int ni = o >> 7, kw = o & 127;
        int which = kw >> 6, k = kw & 63;
        const float* wp = ew0 + (which ? DL * 64 : 0) + k;
        float s = which ? 0.f : eb0[k];
#pragma unroll
        for (int c = 0; c < DL; ++c) s += hs[ni][c] * wp[c * 64];
        (which ? V : U)[(row0 + ni) * 64 + k] = s;
    }
}

// One wave per (b,i). Edge MLP (f16 MFMA) + j-aggregation + node MLP epilogue.
// FINAL=0: epilogue also emits h', U', V' for the next step.
// FINAL=1: epilogue emits tanh(h'@out_w+out_b).
template <int FINAL>
__global__ __launch_bounds__(64, 4) void k_edge_fused(
    const float* __restrict__ h, const float* __restrict__ U, const float* __restrict__ V,
    const float* __restrict__ w0, const _Float16* __restrict__ PW,
    const float* __restrict__ b1,
    const float* __restrict__ w0n, const float* __restrict__ b0n,
    const float* __restrict__ w1n, const float* __restrict__ b1n,
    const float* __restrict__ wA, const float* __restrict__ bA,
    float* __restrict__ hout, float* __restrict__ Uo, float* __restrict__ Vo,
    float* __restrict__ out) {
    __shared__ float dist[112];
    __shared__ float hs[DL];
    __shared__ float aggs[64];
    __shared__ float t0s[64];
    __shared__ float hs2[DL];

    int bi = blockIdx.x;
    int b = bi / NN;
    int lane = threadIdx.x;
    int q = lane >> 4, kk = lane & 15;

    // distances (2 j's per lane; j>=100 clamped, rows masked later) + stage h_i
    {
        const float* hi = h + bi * DL;
        int j2 = 64 + lane;
        int j2c = j2 < NN ? j2 : NN - 1;
        const float* hj1 = h + (b * NN + lane) * DL;
        const float* hj2 = h + (b * NN + j2c) * DL;
        float s1 = 0.f, s2 = 0.f;
#pragma unroll
        for (int c = 0; c < DL; ++c) {
            float hic = hi[c];
            float d1 = hic - hj1[c]; s1 += d1 * d1;
            float d2 = hic - hj2[c]; s2 += d2 * d2;
        }
        dist[lane] = sqrtf(s1 + 1e-12f);
        if (lane < 48) dist[j2] = sqrtf(s2 + 1e-12f);
        if (lane < DL) hs[lane] = hi[lane];
    }

    // per-lane invariant channels c in [q*8, q*8+8) and [32+q*8, ...)
    int cb = q * 8;
    float ui[16], wdv[16];
    {
        const float* Up = U + bi * 64;
        const float* Wd = w0 + 64 * 64;  // dist row of W0
#pragma unroll
        for (int e = 0; e < 8; ++e) {
            ui[e] = Up[cb + e];
            ui[8 + e] = Up[32 + cb + e];
            wdv[e] = Wd[cb + e];
            wdv[8 + e] = Wd[32 + cb + e];
        }
    }
    f16x8 Bf[4][2];
    {
        const f16x8* pw = (const f16x8*)PW;
#pragma unroll
        for (int kt = 0; kt < 4; ++kt)
#pragma unroll
            for (int hf = 0; hf < 2; ++hf) Bf[kt][hf] = pw[(kt * 2 + hf) * 64 + lane];
    }
    float b1v[4];
#pragma unroll
    for (int kt = 0; kt < 4; ++kt) b1v[kt] = b1[kt * 16 + kk];

    f32x4 sacc[4];
#pragma unroll
    for (int kt = 0; kt < 4; ++kt) sacc[kt] = (f32x4){0.f, 0.f, 0.f, 0.f};

    __syncthreads();

    for (int jt = 0; jt < 7; ++jt) {
        int j = jt * 16 + kk;  // A-frag row m = lane&15
        int jc = j < NN ? j : NN - 1;
        float dj = dist[j];
        const float* vr = V + (size_t)(b * NN + jc) * 64;
        f16x8 A0, A1;
#pragma unroll
        for (int e = 0; e < 8; ++e) {
            A0[e] = (_Float16)lrelu(ui[e] + vr[cb + e] + dj * wdv[e]);
            A1[e] = (_Float16)lrelu(ui[8 + e] + vr[32 + cb + e] + dj * wdv[8 + e]);
        }
#pragma unroll
        for (int kt = 0; kt < 4; ++kt) {
            f32x4 a = {0.f, 0.f, 0.f, 0.f};
            a = __builtin_amdgcn_mfma_f32_16x16x32_f16(A0, Bf[kt][0], a, 0, 0, 0);
            a = __builtin_amdgcn_mfma_f32_16x16x32_f16(A1, Bf[kt][1], a, 0, 0, 0);
#pragma unroll
            for (int r = 0; r < 4; ++r) {
                int jr = jt * 16 + q * 4 + r;  // C/D row
                float v = lrelu(a[r] + b1v[kt]);
                sacc[kt][r] += (jr < NN) ? v : 0.f;
            }
        }
    }

#pragma unroll
    for (int kt = 0; kt < 4; ++kt) {
        float s = sacc[kt][0] + sacc[kt][1] + sacc[kt][2] + sacc[kt][3];
        s += __shfl_xor(s, 16);
        s += __shfl_xor(s, 32);
        if (q == 0) aggs[kt * 16 + kk] = s;
    }
    __syncthreads();

    // node MLP layer 0: k = lane, input = [h_i(32), agg(64)]
    {
        float s = b0n[lane];
#pragma unroll 8
        for (int c = 0; c < DL; ++c) s += hs[c] * w0n[c * 64 + lane];
#pragma unroll 8
        for (int c = 0; c < 64; ++c) s += aggs[c] * w0n[(DL + c) * 64 + lane];
        t0s[lane] = lrelu(s);
    }
    __syncthreads();
    if (lane < DL) {  // node MLP layer 1
        float s = b1n[lane];
#pragma unroll 8
        for (int c = 0; c < 64; ++c) s += t0s[c] * w1n[c * DL + lane];
        float hv = lrelu(s);
        hs2[lane] = hv;
        if (!FINAL) hout[bi * DL + lane] = hv;
    }
    __syncthreads();
    if (FINAL) {
        if (lane < 3) {
            float s = bA[lane];
#pragma unroll
            for (int c = 0; c < DL; ++c) s += hs2[c] * wA[c * 3 + lane];
            out[bi * 3 + lane] = tanhf(s);
        }
    } else {  // U/V for the next step
        float s = bA[lane];
        float s2 = 0.f;
        const float* wu = wA + lane;
        const float* wv = wA + DL * 64 + lane;
#pragma unroll
        for (int c = 0; c < DL; ++c) {
            float hv = hs2[c];
            s += hv * wu[c * 64];
            s2 += hv * wv[c * 64];
        }
        Uo[bi * 64 + lane] = s;
        Vo[bi * 64 + lane] = s2;
    }
}

extern "C" void kernel_launch(void* const* d_in, const int* in_sizes, int n_in,
                              void* d_out, int out_size, void* d_ws, size_t ws_size,
                              hipStream_t stream) {
    const float* x     = (const float*)d_in[0];
    const float* lin_w = (const float*)d_in[1];
    const float* lin_b = (const float*)d_in[2];
    const float* ew0[2] = {(const float*)d_in[3],  (const float*)d_in[11]};
    const float* eb0[2] = {(const float*)d_in[4],  (const float*)d_in[12]};
    const float* ew1[2] = {(const float*)d_in[5],  (const float*)d_in[13]};
    const float* eb1[2] = {(const float*)d_in[6],  (const float*)d_in[14]};
    const float* nw0[2] = {(const float*)d_in[7],  (const float*)d_in[15]};
    const float* nb0[2] = {(const float*)d_in[8],  (const float*)d_in[16]};
    const float* nw1[2] = {(const float*)d_in[9],  (const float*)d_in[17]};
    const float* nb1[2] = {(const float*)d_in[10], (const float*)d_in[18]};
    const float* ow = (const float*)d_in[19];
    const float* ob = (const float*)d_in[20];
    float* out = (float*)d_out;

    float* h   = (float*)d_ws;          // 6400 x 32
    float* h2  = h + 204800;            // 6400 x 32
    float* U   = h2 + 204800;           // 6400 x 64
    float* V   = U + 409600;            // 6400 x 64
    float* U2  = V + 409600;            // 6400 x 64
    float* V2  = U2 + 409600;           // 6400 x 64
    _Float16* PW = (_Float16*)(V2 + 409600);  // 2 x 4096 f16

    k_pre<<<1602, 256, 0, stream>>>(x, lin_w, lin_b, ew0[0], eb0[0], ew1[0], ew1[1],
                                    h, U, V, PW);
    k_edge_fused<0><<<BN, 64, 0, stream>>>(h, U, V, ew0[0], PW, eb1[0],
                                           nw0[0], nb0[0], nw1[0], nb1[0],
                                           ew0[1], eb0[1], h2, U2, V2, nullptr);
    k_edge_fused<1><<<BN, 64, 0, stream>>>(h2, U2, V2, ew0[1], PW + 4096, eb1[1],
                                           nw0[1], nb0[1], nw1[1], nb1[1],
                                           ow, ob, nullptr, nullptr, nullptr, out);
}

// Round 4
// 214.808 us; speedup vs baseline: 1.1418x; 1.0725x over previous
//
#include <hip/hip_runtime.h>

#define NB 64
#define NN 100
#define DL 32
#define BN (NB * NN)  // 6400

typedef _Float16 f16x8 __attribute__((ext_vector_type(8)));
typedef float f32x4 __attribute__((ext_vector_type(4)));

static __device__ __forceinline__ float lrelu(float x) { return fmaxf(x, 0.1f * x); }

// Fused: h = x@lin_w+lin_b, U/V for step 0, and W1 f16 B-fragment prep (both steps).
// Blocks 0..1599: 4 (b,n) rows each. Blocks 1600..1601: PW for step 0/1.
__global__ __launch_bounds__(256) void k_pre(
    const float* __restrict__ x, const float* __restrict__ lw, const float* __restrict__ lb,
    const float* __restrict__ ew0, const float* __restrict__ eb0,
    const float* __restrict__ w1a, const float* __restrict__ w1b,
    float* __restrict__ h, float* __restrict__ U, float* __restrict__ V,
    _Float16* __restrict__ PW) {
    int blk = blockIdx.x;
    int t = threadIdx.x;
    if (blk >= 1600) {  // B-fragment swizzle: PW[step][kt][hf][lane][jj]
        int step = blk - 1600;
        const float* w1 = step ? w1b : w1a;
        _Float16* dst = PW + step * 4096;
#pragma unroll
        for (int u = 0; u < 16; ++u) {
            int idx = t * 16 + u;
            int jj = idx & 7, lane = (idx >> 3) & 63, hf = (idx >> 9) & 1, kt = idx >> 10;
            int c = hf * 32 + (lane >> 4) * 8 + jj;
            int k = kt * 16 + (lane & 15);
            dst[idx] = (_Float16)w1[c * 64 + k];
        }
        return;
    }
    __shared__ float xs[DL];
    __shared__ float hs[4][DL];
    int row0 = blk * 4;
    int b = row0 / NN;  // 4-row group never crosses a batch boundary (100 % 4 == 0)
    if (t < DL) xs[t] = x[b * DL + t];
    __syncthreads();
    if (t < 128) {
        int ni = t >> 5, c = t & 31;
        int n = (row0 + ni) % NN;
        float s = lb[n * DL + c];
#pragma unroll
        for (int cc = 0; cc < DL; ++cc) s += xs[cc] * lw[cc * 3200 + n * DL + c];
        hs[ni][c] = s;
        h[(row0 + ni) * DL + c] = s;
    }
    __syncthreads();
#pragma unroll
    for (int r = 0; r < 2; ++r) {
        int o = r * 256 + t;  // 0..511 : 4 rows x (64 U + 64 V)
        int ni = o >> 7, kw = o & 127;
        int which = kw >> 6, k = kw & 63;
        const float* wp = ew0 + (which ? DL * 64 : 0) + k;
        float s = which ? 0.f : eb0[k];
#pragma unroll
        for (int c = 0; c < DL; ++c) s += hs[ni][c] * wp[c * 64];
        (which ? V : U)[(row0 + ni) * 64 + k] = s;
    }
}

// One wave per (b,i). Edge MLP (f16 MFMA) + j-aggregation + node MLP epilogue.
// waves_per_eu pinned at (4,4): VGPR budget 128, allocator may NOT chase higher
// occupancy by spilling (R3 lesson: [4,10] range -> 64 VGPRs + 148 MB spill traffic).
template <int FINAL>
__global__ __launch_bounds__(64) __attribute__((amdgpu_waves_per_eu(4, 4))) void k_edge_fused(
    const float* __restrict__ h, const float* __restrict__ U, const float* __restrict__ V,
    const float* __restrict__ w0, const _Float16* __restrict__ PW,
    const float* __restrict__ b1,
    const float* __restrict__ w0n, const float* __restrict__ b0n,
    const float* __restrict__ w1n, const float* __restrict__ b1n,
    const float* __restrict__ wA, const float* __restrict__ bA,
    float* __restrict__ hout, float* __restrict__ Uo, float* __restrict__ Vo,
    float* __restrict__ out) {
    __shared__ float dist[112];
    __shared__ float hs[DL];
    __shared__ float aggs[64];
    __shared__ float t0s[64];
    __shared__ float hs2[DL];

    int bi = blockIdx.x;
    int b = bi / NN;
    int lane = threadIdx.x;
    int q = lane >> 4, kk = lane & 15;

    // distances (2 j's per lane; j>=100 clamped, rows masked later) + stage h_i
    {
        const float* hi = h + bi * DL;
        int j2 = 64 + lane;
        int j2c = j2 < NN ? j2 : NN - 1;
        const float* hj1 = h + (b * NN + lane) * DL;
        const float* hj2 = h + (b * NN + j2c) * DL;
        float s1 = 0.f, s2 = 0.f;
#pragma unroll
        for (int c = 0; c < DL; ++c) {
            float hic = hi[c];
            float d1 = hic - hj1[c]; s1 += d1 * d1;
            float d2 = hic - hj2[c]; s2 += d2 * d2;
        }
        dist[lane] = sqrtf(s1 + 1e-12f);
        if (lane < 48) dist[j2] = sqrtf(s2 + 1e-12f);
        if (lane < DL) hs[lane] = hi[lane];
    }

    // per-lane invariant channels c in [q*8, q*8+8) and [32+q*8, ...)
    int cb = q * 8;
    float ui[16], wdv[16];
    {
        const float* Up = U + bi * 64;
        const float* Wd = w0 + 64 * 64;  // dist row of W0
#pragma unroll
        for (int e = 0; e < 8; ++e) {
            ui[e] = Up[cb + e];
            ui[8 + e] = Up[32 + cb + e];
            wdv[e] = Wd[cb + e];
            wdv[8 + e] = Wd[32 + cb + e];
        }
    }
    f16x8 Bf[4][2];
    {
        const f16x8* pw = (const f16x8*)PW;
#pragma unroll
        for (int kt = 0; kt < 4; ++kt)
#pragma unroll
            for (int hf = 0; hf < 2; ++hf) Bf[kt][hf] = pw[(kt * 2 + hf) * 64 + lane];
    }
    float b1v[4];
#pragma unroll
    for (int kt = 0; kt < 4; ++kt) b1v[kt] = b1[kt * 16 + kk];

    f32x4 sacc[4];
#pragma unroll
    for (int kt = 0; kt < 4; ++kt) sacc[kt] = (f32x4){0.f, 0.f, 0.f, 0.f};

    __syncthreads();

    for (int jt = 0; jt < 7; ++jt) {
        int j = jt * 16 + kk;  // A-frag row m = lane&15
        int jc = j < NN ? j : NN - 1;
        float dj = dist[j];
        const float4* vr = (const float4*)(V + (size_t)(b * NN + jc) * 64 + cb);
        float4 v0 = vr[0], v1 = vr[1];      // c in [cb, cb+8)
        float4 v2 = vr[8], v3 = vr[9];      // c in [32+cb, 32+cb+8)
        f16x8 A0, A1;
        A0[0] = (_Float16)lrelu(ui[0] + v0.x + dj * wdv[0]);
        A0[1] = (_Float16)lrelu(ui[1] + v0.y + dj * wdv[1]);
        A0[2] = (_Float16)lrelu(ui[2] + v0.z + dj * wdv[2]);
        A0[3] = (_Float16)lrelu(ui[3] + v0.w + dj * wdv[3]);
        A0[4] = (_Float16)lrelu(ui[4] + v1.x + dj * wdv[4]);
        A0[5] = (_Float16)lrelu(ui[5] + v1.y + dj * wdv[5]);
        A0[6] = (_Float16)lrelu(ui[6] + v1.z + dj * wdv[6]);
        A0[7] = (_Float16)lrelu(ui[7] + v1.w + dj * wdv[7]);
        A1[0] = (_Float16)lrelu(ui[8] + v2.x + dj * wdv[8]);
        A1[1] = (_Float16)lrelu(ui[9] + v2.y + dj * wdv[9]);
        A1[2] = (_Float16)lrelu(ui[10] + v2.z + dj * wdv[10]);
        A1[3] = (_Float16)lrelu(ui[11] + v2.w + dj * wdv[11]);
        A1[4] = (_Float16)lrelu(ui[12] + v3.x + dj * wdv[12]);
        A1[5] = (_Float16)lrelu(ui[13] + v3.y + dj * wdv[13]);
        A1[6] = (_Float16)lrelu(ui[14] + v3.z + dj * wdv[14]);
        A1[7] = (_Float16)lrelu(ui[15] + v3.w + dj * wdv[15]);
#pragma unroll
        for (int kt = 0; kt < 4; ++kt) {
            f32x4 a = {0.f, 0.f, 0.f, 0.f};
            a = __builtin_amdgcn_mfma_f32_16x16x32_f16(A0, Bf[kt][0], a, 0, 0, 0);
            a = __builtin_amdgcn_mfma_f32_16x16x32_f16(A1, Bf[kt][1], a, 0, 0, 0);
#pragma unroll
            for (int r = 0; r < 4; ++r) {
                int jr = jt * 16 + q * 4 + r;  // C/D row
                float v = lrelu(a[r] + b1v[kt]);
                sacc[kt][r] += (jr < NN) ? v : 0.f;
            }
        }
    }

#pragma unroll
    for (int kt = 0; kt < 4; ++kt) {
        float s = sacc[kt][0] + sacc[kt][1] + sacc[kt][2] + sacc[kt][3];
        s += __shfl_xor(s, 16);
        s += __shfl_xor(s, 32);
        if (q == 0) aggs[kt * 16 + kk] = s;
    }
    __syncthreads();

    // node MLP layer 0: k = lane, input = [h_i(32), agg(64)]
    {
        float s = b0n[lane];
#pragma unroll 8
        for (int c = 0; c < DL; ++c) s += hs[c] * w0n[c * 64 + lane];
#pragma unroll 8
        for (int c = 0; c < 64; ++c) s += aggs[c] * w0n[(DL + c) * 64 + lane];
        t0s[lane] = lrelu(s);
    }
    __syncthreads();
    if (lane < DL) {  // node MLP layer 1
        float s = b1n[lane];
#pragma unroll 8
        for (int c = 0; c < 64; ++c) s += t0s[c] * w1n[c * DL + lane];
        float hv = lrelu(s);
        hs2[lane] = hv;
        if (!FINAL) hout[bi * DL + lane] = hv;
    }
    __syncthreads();
    if (FINAL) {
        if (lane < 3) {
            float s = bA[lane];
#pragma unroll
            for (int c = 0; c < DL; ++c) s += hs2[c] * wA[c * 3 + lane];
            out[bi * 3 + lane] = tanhf(s);
        }
    } else {  // U/V for the next step
        float s = bA[lane];
        float s2 = 0.f;
        const float* wu = wA + lane;
        const float* wv = wA + DL * 64 + lane;
#pragma unroll
        for (int c = 0; c < DL; ++c) {
            float hv = hs2[c];
            s += hv * wu[c * 64];
            s2 += hv * wv[c * 64];
        }
        Uo[bi * 64 + lane] = s;
        Vo[bi * 64 + lane] = s2;
    }
}

extern "C" void kernel_launch(void* const* d_in, const int* in_sizes, int n_in,
                              void* d_out, int out_size, void* d_ws, size_t ws_size,
                              hipStream_t stream) {
    const float* x     = (const float*)d_in[0];
    const float* lin_w = (const float*)d_in[1];
    const float* lin_b = (const float*)d_in[2];
    const float* ew0[2] = {(const float*)d_in[3],  (const float*)d_in[11]};
    const float* eb0[2] = {(const float*)d_in[4],  (const float*)d_in[12]};
    const float* ew1[2] = {(const float*)d_in[5],  (const float*)d_in[13]};
    const float* eb1[2] = {(const float*)d_in[6],  (const float*)d_in[14]};
    const float* nw0[2] = {(const float*)d_in[7],  (const float*)d_in[15]};
    const float* nb0[2] = {(const float*)d_in[8],  (const float*)d_in[16]};
    const float* nw1[2] = {(const float*)d_in[9],  (const float*)d_in[17]};
    const float* nb1[2] = {(const float*)d_in[10], (const float*)d_in[18]};
    const float* ow = (const float*)d_in[19];
    const float* ob = (const float*)d_in[20];
    float* out = (float*)d_out;

    float* h   = (float*)d_ws;          // 6400 x 32
    float* h2  = h + 204800;            // 6400 x 32
    float* U   = h2 + 204800;           // 6400 x 64
    float* V   = U + 409600;            // 6400 x 64
    float* U2  = V + 409600;            // 6400 x 64
    float* V2  = U2 + 409600;           // 6400 x 64
    _Float16* PW = (_Float16*)(V2 + 409600);  // 2 x 4096 f16

    k_pre<<<1602, 256, 0, stream>>>(x, lin_w, lin_b, ew0[0], eb0[0], ew1[0], ew1[1],
                                    h, U, V, PW);
    k_edge_fused<0><<<BN, 64, 0, stream>>>(h, U, V, ew0[0], PW, eb1[0],
                                           nw0[0], nb0[0], nw1[0], nb1[0],
                                           ew0[1], eb0[1], h2, U2, V2, nullptr);
    k_edge_fused<1><<<BN, 64, 0, stream>>>(h2, U2, V2, ew0[1], PW + 4096, eb1[1],
                                           nw0[1], nb0[1], nw1[1], nb1[1],
                                           ow, ob, nullptr, nullptr, nullptr, out);
}

// Round 5
// 188.857 us; speedup vs baseline: 1.2987x; 1.1374x over previous
//
#include <hip/hip_runtime.h>

#define NB 64
#define NN 100
#define DL 32
#define BN (NB * NN)  // 6400

typedef _Float16 f16x8 __attribute__((ext_vector_type(8)));
typedef _Float16 f16x4 __attribute__((ext_vector_type(4)));
typedef float f32x4 __attribute__((ext_vector_type(4)));

static __device__ __forceinline__ float lrelu(float x) { return fmaxf(x, 0.1f * x); }

// Fused: h = x@lin_w+lin_b, U/V for step 0, and W1 f16 B-fragment prep (both steps).
// Blocks 0..1599: 4 (b,n) rows each. Blocks 1600..1601: PW for step 0/1.
__global__ __launch_bounds__(256) void k_pre(
    const float* __restrict__ x, const float* __restrict__ lw, const float* __restrict__ lb,
    const float* __restrict__ ew0, const float* __restrict__ eb0,
    const float* __restrict__ w1a, const float* __restrict__ w1b,
    float* __restrict__ h, float* __restrict__ U, float* __restrict__ V,
    _Float16* __restrict__ PW) {
    int blk = blockIdx.x;
    int t = threadIdx.x;
    if (blk >= 1600) {  // B-fragment swizzle: PW[step][kt][hf][lane][jj]
        int step = blk - 1600;
        const float* w1 = step ? w1b : w1a;
        _Float16* dst = PW + step * 4096;
#pragma unroll
        for (int u = 0; u < 16; ++u) {
            int idx = t * 16 + u;
            int jj = idx & 7, lane = (idx >> 3) & 63, hf = (idx >> 9) & 1, kt = idx >> 10;
            int c = hf * 32 + (lane >> 4) * 8 + jj;
            int k = kt * 16 + (lane & 15);
            dst[idx] = (_Float16)w1[c * 64 + k];
        }
        return;
    }
    __shared__ float xs[DL];
    __shared__ float hs[4][DL];
    int row0 = blk * 4;
    int b = row0 / NN;  // 4-row group never crosses a batch boundary (100 % 4 == 0)
    if (t < DL) xs[t] = x[b * DL + t];
    __syncthreads();
    if (t < 128) {
        int ni = t >> 5, c = t & 31;
        int n = (row0 + ni) % NN;
        float s = lb[n * DL + c];
#pragma unroll
        for (int cc = 0; cc < DL; ++cc) s += xs[cc] * lw[cc * 3200 + n * DL + c];
        hs[ni][c] = s;
        h[(row0 + ni) * DL + c] = s;
    }
    __syncthreads();
#pragma unroll
    for (int r = 0; r < 2; ++r) {
        int o = r * 256 + t;  // 0..511 : 4 rows x (64 U + 64 V)
        int ni = o >> 7, kw = o & 127;
        int which = kw >> 6, k = kw & 63;
        const float* wp = ew0 + (which ? DL * 64 : 0) + k;
        float s = which ? 0.f : eb0[k];
#pragma unroll
        for (int c = 0; c < DL; ++c) s += hs[ni][c] * wp[c * 64];
        (which ? V : U)[(row0 + ni) * 64 + k] = s;
    }
}

// 256 threads per (b,i). Cooperative f16 P-tile in LDS (double-buffered, 1 barrier
// per tile), wave w owns k-tile kt=w (only 2 B-frags + 1 acc per lane -> ~50 VGPRs,
// no spill; R3/R4 lesson: per-wave-everything needed 118 regs and spilled 68 MB).
// P rows padded to 72 f16 (bank stride 36 -> <=2-way conflicts, free per m136).
template <int FINAL>
__global__ __launch_bounds__(256) void k_edge_fused(
    const float* __restrict__ h, const float* __restrict__ U, const float* __restrict__ V,
    const float* __restrict__ w0, const _Float16* __restrict__ PW,
    const float* __restrict__ b1,
    const float* __restrict__ w0n, const float* __restrict__ b0n,
    const float* __restrict__ w1n, const float* __restrict__ b1n,
    const float* __restrict__ wA, const float* __restrict__ bA,
    float* __restrict__ hout, float* __restrict__ Uo, float* __restrict__ Vo,
    float* __restrict__ out) {
    __shared__ float dist[112];
    __shared__ _Float16 P[2][16][72];
    __shared__ float hs[DL];
    __shared__ float aggs[64];
    __shared__ float t0s[64];
    __shared__ float hs2[DL];
    __shared__ float red[4][64];

    int bi = blockIdx.x;
    int b = bi / NN;
    int t = threadIdx.x;
    int w = t >> 6, lane = t & 63, q = lane >> 4, kk = lane & 15;

    // distances dist[i, j] for all j (clamped beyond 99; rows masked in epilogue)
    if (t < 112) {
        int j = t < NN ? t : NN - 1;
        const float* hi = h + bi * DL;
        const float* hj = h + (b * NN + j) * DL;
        float s = 0.f;
#pragma unroll
        for (int c = 0; c < DL; ++c) {
            float d = hi[c] - hj[c];
            s += d * d;
        }
        dist[t] = sqrtf(s + 1e-12f);
    }
    if (t < DL) hs[t] = h[bi * DL + t];

    // P-build role: thread handles row bj, channels c0..c0+3
    int bj = t & 15, c0 = (t >> 4) * 4;
    float4 uvq = *(const float4*)(U + bi * 64 + c0);        // U_i + b0 folded
    float4 wdq = *(const float4*)(w0 + 64 * 64 + c0);       // dist row of W0

    // MFMA role: wave w owns kt = w
    const f16x8* pw = (const f16x8*)PW;
    f16x8 Bf0 = pw[(w * 2 + 0) * 64 + lane];
    f16x8 Bf1 = pw[(w * 2 + 1) * 64 + lane];
    float b1k = b1[w * 16 + kk];
    f32x4 sacc = {0.f, 0.f, 0.f, 0.f};

    __syncthreads();

    {  // build tile 0
        float dj = dist[bj];
        float4 v4 = *(const float4*)(V + (size_t)(b * NN + bj) * 64 + c0);
        f16x4 pv;
        pv[0] = (_Float16)lrelu(uvq.x + v4.x + dj * wdq.x);
        pv[1] = (_Float16)lrelu(uvq.y + v4.y + dj * wdq.y);
        pv[2] = (_Float16)lrelu(uvq.z + v4.z + dj * wdq.z);
        pv[3] = (_Float16)lrelu(uvq.w + v4.w + dj * wdq.w);
        *(f16x4*)&P[0][bj][c0] = pv;
    }
    __syncthreads();

#pragma unroll
    for (int jt = 0; jt < 7; ++jt) {
        f16x8 A0 = *(const f16x8*)&P[jt & 1][kk][q * 8];
        f16x8 A1 = *(const f16x8*)&P[jt & 1][kk][32 + q * 8];
        float4 vn;
        float djn = 0.f;
        if (jt < 6) {  // prefetch next tile's V row early (hidden behind MFMA)
            int j = (jt + 1) * 16 + bj;
            int jc = j < NN ? j : NN - 1;
            djn = dist[j];
            vn = *(const float4*)(V + (size_t)(b * NN + jc) * 64 + c0);
        }
        f32x4 a = {0.f, 0.f, 0.f, 0.f};
        a = __builtin_amdgcn_mfma_f32_16x16x32_f16(A0, Bf0, a, 0, 0, 0);
        a = __builtin_amdgcn_mfma_f32_16x16x32_f16(A1, Bf1, a, 0, 0, 0);
#pragma unroll
        for (int r = 0; r < 4; ++r) {
            int jr = jt * 16 + q * 4 + r;  // C/D row
            float v = lrelu(a[r] + b1k);
            sacc[r] += (jr < NN) ? v : 0.f;
        }
        if (jt < 6) {
            f16x4 pv;
            pv[0] = (_Float16)lrelu(uvq.x + vn.x + djn * wdq.x);
            pv[1] = (_Float16)lrelu(uvq.y + vn.y + djn * wdq.y);
            pv[2] = (_Float16)lrelu(uvq.z + vn.z + djn * wdq.z);
            pv[3] = (_Float16)lrelu(uvq.w + vn.w + djn * wdq.w);
            *(f16x4*)&P[(jt + 1) & 1][bj][c0] = pv;
        }
        __syncthreads();
    }

    // wave w holds C[16j x 16k_w]: sum rows in-lane, then over q; col kk -> k=w*16+kk
    {
        float s = sacc[0] + sacc[1] + sacc[2] + sacc[3];
        s += __shfl_xor(s, 16);
        s += __shfl_xor(s, 32);
        if (q == 0) aggs[w * 16 + kk] = s;
    }
    __syncthreads();

    // node MLP layer 0: 256 threads, k = t&63, partial p = t>>6 over 24 inputs
    {
        int k = t & 63, p = t >> 6;
        float s = 0.f;
#pragma unroll
        for (int ii = 0; ii < 24; ++ii) {
            int c = p * 24 + ii;  // wave-uniform branch
            float xv = (c < DL) ? hs[c] : aggs[c - DL];
            s += xv * w0n[c * 64 + k];
        }
        red[p][k] = s;
    }
    __syncthreads();
    if (t < 64) t0s[t] = lrelu(b0n[t] + red[0][t] + red[1][t] + red[2][t] + red[3][t]);
    __syncthreads();
    if (t < 64) {  // node MLP layer 1: k = t&31, partial p = t>>5 over 32 inputs
        int k = t & 31, p = t >> 5;
        float s = 0.f;
#pragma unroll
        for (int ii = 0; ii < 32; ++ii) {
            int c = p * 32 + ii;
            s += t0s[c] * w1n[c * DL + k];
        }
        red[p][k] = s;
    }
    __syncthreads();
    if (t < DL) {
        float hv = lrelu(b1n[t] + red[0][t] + red[1][t]);
        hs2[t] = hv;
        if (!FINAL) hout[bi * DL + t] = hv;
    }
    __syncthreads();
    if (FINAL) {
        if (t < 3) {
            float s = bA[t];
#pragma unroll
            for (int c = 0; c < DL; ++c) s += hs2[c] * wA[c * 3 + t];
            out[bi * 3 + t] = tanhf(s);
        }
    } else if (t < 128) {  // U/V for the next step
        int k = t & 63, which = t >> 6;
        const float* wp = wA + (which ? DL * 64 : 0) + k;
        float s = which ? 0.f : bA[k];
#pragma unroll
        for (int c = 0; c < DL; ++c) s += hs2[c] * wp[c * 64];
        (which ? Vo : Uo)[bi * 64 + k] = s;
    }
}

extern "C" void kernel_launch(void* const* d_in, const int* in_sizes, int n_in,
                              void* d_out, int out_size, void* d_ws, size_t ws_size,
                              hipStream_t stream) {
    const float* x     = (const float*)d_in[0];
    const float* lin_w = (const float*)d_in[1];
    const float* lin_b = (const float*)d_in[2];
    const float* ew0[2] = {(const float*)d_in[3],  (const float*)d_in[11]};
    const float* eb0[2] = {(const float*)d_in[4],  (const float*)d_in[12]};
    const float* ew1[2] = {(const float*)d_in[5],  (const float*)d_in[13]};
    const float* eb1[2] = {(const float*)d_in[6],  (const float*)d_in[14]};
    const float* nw0[2] = {(const float*)d_in[7],  (const float*)d_in[15]};
    const float* nb0[2] = {(const float*)d_in[8],  (const float*)d_in[16]};
    const float* nw1[2] = {(const float*)d_in[9],  (const float*)d_in[17]};
    const float* nb1[2] = {(const float*)d_in[10], (const float*)d_in[18]};
    const float* ow = (const float*)d_in[19];
    const float* ob = (const float*)d_in[20];
    float* out = (float*)d_out;

    float* h   = (float*)d_ws;          // 6400 x 32
    float* h2  = h + 204800;            // 6400 x 32
    float* U   = h2 + 204800;           // 6400 x 64
    float* V   = U + 409600;            // 6400 x 64
    float* U2  = V + 409600;            // 6400 x 64
    float* V2  = U2 + 409600;           // 6400 x 64
    _Float16* PW = (_Float16*)(V2 + 409600);  // 2 x 4096 f16

    k_pre<<<1602, 256, 0, stream>>>(x, lin_w, lin_b, ew0[0], eb0[0], ew1[0], ew1[1],
                                    h, U, V, PW);
    k_edge_fused<0><<<BN, 256, 0, stream>>>(h, U, V, ew0[0], PW, eb1[0],
                                            nw0[0], nb0[0], nw1[0], nb1[0],
                                            ew0[1], eb0[1], h2, U2, V2, nullptr);
    k_edge_fused<1><<<BN, 256, 0, stream>>>(h2, U2, V2, ew0[1], PW + 4096, eb1[1],
                                            nw0[1], nb0[1], nw1[1], nb1[1],
                                            ow, ob, nullptr, nullptr, nullptr, out);
}